// Round 5
// baseline (199.241 us; speedup 1.0000x reference)
//
#include <hip/hip_runtime.h>

// LogSumExpPooling2D: x (8,256,256,64) f32 NHWC ->
// out (1,128,128,64): (1/100)*logsumexp(100*x) over 2x2 stride-2 window AND batch.
//
// R5 PROBE: R3 kernel + a second, numerically-idempotent full read pass
// (fmax-fold of the same data; runtime extra=0 offset defeats CSE). Forces
// +134 MB of HBM reads with zero semantic change. Delta(dur_us) measures the
// kernel's marginal read cost and resolves kernel-time vs harness-fixed-time:
//   +~22 us  -> kernel was ~23 us, HBM-bound -> roofline.
//   +~65 us  -> kernel ~65 us, reads capped at ~2 TB/s -> investigate.

constexpr float SCALE = 100.0f;
constexpr float INV_SCALE = 0.01f;

__device__ inline void pair_merge(float& m, float& s, float m2, float s2) {
    const float mn = fmaxf(m, m2);
    s = s * __expf((m - mn) * SCALE) + s2 * __expf((m2 - mn) * SCALE);
    m = mn;
}

__device__ inline void chunk_merge(const float4& v0, const float4& v1,
                                   float m[4], float s[4]) {
    const float e0[4] = {v0.x, v0.y, v0.z, v0.w};
    const float e1[4] = {v1.x, v1.y, v1.z, v1.w};
#pragma unroll
    for (int j = 0; j < 4; ++j) {
        const float cm = fmaxf(e0[j], e1[j]);
        const float cs = __expf((e0[j] - cm) * SCALE) + __expf((e1[j] - cm) * SCALE);
        pair_merge(m[j], s[j], cm, cs);
    }
}

__device__ inline void max_fold(const float4& v, float m[4]) {
    m[0] = fmaxf(m[0], v.x);
    m[1] = fmaxf(m[1], v.y);
    m[2] = fmaxf(m[2], v.z);
    m[3] = fmaxf(m[3], v.w);
}

__global__ __launch_bounds__(256) void lse_pool_kernel(const float* __restrict__ x,
                                                       float* __restrict__ out,
                                                       size_t extra) {
    const int tid = blockIdx.x * 256 + threadIdx.x;
    const int l   = tid & 63;        // lane
    const int wv  = tid >> 6;        // global wave 0..4095
    const int ho  = wv >> 5;         // output row 0..127
    const int p0  = (wv & 31) << 3;  // input pixel-column base

    const size_t NS = (size_t)256 * 256 * 64;  // batch stride (floats)
    const size_t HS = (size_t)256 * 64;        // row stride (floats)
    const float* base = x + (((size_t)(2 * ho) * 256) + (size_t)p0) * 64 + (size_t)(l * 4);

    float mA[4], sA[4], mB[4], sB[4];
#pragma unroll
    for (int j = 0; j < 4; ++j) { mA[j] = -1e30f; sA[j] = 0.f; mB[j] = -1e30f; sB[j] = 0.f; }

    // Pass 1: the real online logsumexp (identical to R3).
#pragma unroll 2
    for (int n = 0; n < 8; ++n) {
        const float* pn = base + (size_t)n * NS;
        const float4 a0 = *reinterpret_cast<const float4*>(pn);
        const float4 b0 = *reinterpret_cast<const float4*>(pn + 256);
        const float4 a1 = *reinterpret_cast<const float4*>(pn + HS);
        const float4 b1 = *reinterpret_cast<const float4*>(pn + HS + 256);
        chunk_merge(a0, a1, mA, sA);
        chunk_merge(b0, b1, mB, sB);
    }

    // Pass 2 (probe): re-read everything, fold maxima (idempotent: mxA<=mA
    // elementwise-equal, so fmax below is a numeric no-op). extra==0 at
    // runtime but opaque to the compiler -> loads can't be CSE'd away.
    float mxA[4] = {-1e30f, -1e30f, -1e30f, -1e30f};
    float mxB[4] = {-1e30f, -1e30f, -1e30f, -1e30f};
    const float* base2 = base + extra;
#pragma unroll 2
    for (int n = 0; n < 8; ++n) {
        const float* pn = base2 + (size_t)n * NS;
        max_fold(*reinterpret_cast<const float4*>(pn),            mxA);
        max_fold(*reinterpret_cast<const float4*>(pn + 256),      mxB);
        max_fold(*reinterpret_cast<const float4*>(pn + HS),       mxA);
        max_fold(*reinterpret_cast<const float4*>(pn + HS + 256), mxB);
    }
#pragma unroll
    for (int j = 0; j < 4; ++j) {
        mA[j] = fmaxf(mA[j], mxA[j]);   // no-op numerically
        mB[j] = fmaxf(mB[j], mxB[j]);
    }

    // dw-pair merge: lanes l and l^16 hold adjacent pixel columns.
#pragma unroll
    for (int j = 0; j < 4; ++j) {
        pair_merge(mA[j], sA[j], __shfl_xor(mA[j], 16), __shfl_xor(sA[j], 16));
        pair_merge(mB[j], sB[j], __shfl_xor(mB[j], 16), __shfl_xor(sB[j], 16));
    }

    if ((l & 16) == 0) {
        float4 rA, rB;
        rA.x = mA[0] + __logf(sA[0]) * INV_SCALE;
        rA.y = mA[1] + __logf(sA[1]) * INV_SCALE;
        rA.z = mA[2] + __logf(sA[2]) * INV_SCALE;
        rA.w = mA[3] + __logf(sA[3]) * INV_SCALE;
        rB.x = mB[0] + __logf(sB[0]) * INV_SCALE;
        rB.y = mB[1] + __logf(sB[1]) * INV_SCALE;
        rB.z = mB[2] + __logf(sB[2]) * INV_SCALE;
        rB.w = mB[3] + __logf(sB[3]) * INV_SCALE;

        const int c  = (l & 15) << 2;
        const int wo = (p0 >> 1) + (l >> 5);
        const size_t o = ((size_t)ho * 128 + (size_t)wo) * 64 + (size_t)c;
        *reinterpret_cast<float4*>(out + o)          = rA;
        *reinterpret_cast<float4*>(out + o + 2 * 64) = rB;
    }
}

extern "C" void kernel_launch(void* const* d_in, const int* in_sizes, int n_in,
                              void* d_out, int out_size, void* d_ws, size_t ws_size,
                              hipStream_t stream) {
    const float* x = (const float*)d_in[0];
    float* out = (float*)d_out;
    lse_pool_kernel<<<1024, 256, 0, stream>>>(x, out, (size_t)0);
}

// Round 6
// 185.848 us; speedup vs baseline: 1.0721x; 1.0721x over previous
//
#include <hip/hip_runtime.h>

// LogSumExpPooling2D: x (8,256,256,64) f32 NHWC ->
// out (1,128,128,64): (1/100)*logsumexp(100*x) over 2x2 stride-2 window AND batch.
//
// FINAL (R2 structure, probe removed). Session findings:
//  - Kernel reads 134 MB once; input is L3-resident (256 MiB Infinity Cache +
//    harness d_in restore right before the kernel) -> marginal read BW measured
//    at ~9.8 TB/s via the R5 idempotent double-read probe (+13.7 us for +134 MB).
//  - Kernel's own time ~15-25 us (never appears above the harness's 78-us
//    512-MiB poison fills in rocprof top-5); dur_us ~185 is dominated by fixed
//    harness graph work (ws/out poison + d_in restore ~160 us).
//  - Occupancy (16 vs 32 waves/CU), VGPR pressure (200 vs 70), and wave-load
//    shape (4x256B segments vs contiguous 1 KiB) all proven neutral (R1-R4).
// => at the memory-system roofline; no kernel-side lever worth > a few us.

constexpr float SCALE = 100.0f;
constexpr float INV_SCALE = 0.01f;

__global__ __launch_bounds__(256, 6) void lse_pool_kernel(const float* __restrict__ x,
                                                          float* __restrict__ out) {
    // thread -> (ho, wo, channel-group of 4). 16 groups cover C=64.
    const int t   = blockIdx.x * 256 + threadIdx.x;   // 0 .. 128*128*16-1
    const int cg  = t & 15;
    const int pix = t >> 4;        // 0 .. 128*128-1
    const int wo  = pix & 127;
    const int ho  = pix >> 7;
    const int c   = cg << 2;
    const int h0  = ho << 1;
    const int w0  = wo << 1;

    const size_t NSTRIDE = (size_t)256 * 256 * 64;     // one batch image, floats
    const float* p = x + ((size_t)h0 * 256 + (size_t)w0) * 64 + (size_t)c;

    float m[4], s[4];
#pragma unroll
    for (int j = 0; j < 4; ++j) { m[j] = -1e30f; s[j] = 0.0f; }

#pragma unroll
    for (int np = 0; np < 4; ++np) {                   // chunk = batches 2np, 2np+1
        float4 v[8];
#pragma unroll
        for (int k = 0; k < 8; ++k) {                  // k = (n&1)<<2 | dh<<1 | dw
            const int n  = (np << 1) | (k >> 2);
            const int dh = (k >> 1) & 1;
            const int dw = k & 1;
            v[k] = *reinterpret_cast<const float4*>(
                p + (size_t)n * NSTRIDE + (size_t)(dh * 256 + dw) * 64);
        }

        // chunk max per channel
        float cm[4] = { v[0].x, v[0].y, v[0].z, v[0].w };
#pragma unroll
        for (int k = 1; k < 8; ++k) {
            cm[0] = fmaxf(cm[0], v[k].x);
            cm[1] = fmaxf(cm[1], v[k].y);
            cm[2] = fmaxf(cm[2], v[k].z);
            cm[3] = fmaxf(cm[3], v[k].w);
        }

        // chunk sum of exp(100*(v - cm)); args <= 0, no overflow
        float cs[4] = { 0.f, 0.f, 0.f, 0.f };
#pragma unroll
        for (int k = 0; k < 8; ++k) {
            cs[0] += __expf((v[k].x - cm[0]) * SCALE);
            cs[1] += __expf((v[k].y - cm[1]) * SCALE);
            cs[2] += __expf((v[k].z - cm[2]) * SCALE);
            cs[3] += __expf((v[k].w - cm[3]) * SCALE);
        }

        // merge running (m, s) with chunk (cm, cs)
#pragma unroll
        for (int j = 0; j < 4; ++j) {
            const float mn = fmaxf(m[j], cm[j]);
            s[j] = s[j] * __expf((m[j] - mn) * SCALE)
                 + cs[j] * __expf((cm[j] - mn) * SCALE);
            m[j] = mn;
        }
    }

    float4 r;
    r.x = m[0] + __logf(s[0]) * INV_SCALE;
    r.y = m[1] + __logf(s[1]) * INV_SCALE;
    r.z = m[2] + __logf(s[2]) * INV_SCALE;
    r.w = m[3] + __logf(s[3]) * INV_SCALE;

    *reinterpret_cast<float4*>(out + (size_t)pix * 64 + (size_t)c) = r;
}

extern "C" void kernel_launch(void* const* d_in, const int* in_sizes, int n_in,
                              void* d_out, int out_size, void* d_ws, size_t ws_size,
                              hipStream_t stream) {
    const float* x = (const float*)d_in[0];
    float* out = (float*)d_out;
    // 128*128 pixels * 16 channel-groups = 262144 threads / 256 = 1024 blocks
    lse_pool_kernel<<<1024, 256, 0, stream>>>(x, out);
}